// Round 9
// baseline (325.162 us; speedup 1.0000x reference)
//
#include <hip/hip_runtime.h>
#include <hip/hip_bf16.h>
#include <stdint.h>

typedef __hip_bfloat16 bf16;
typedef __attribute__((ext_vector_type(8))) short bf16x8;   // 8 bf16 = 4 VGPRs (MFMA A/B frag)
typedef __attribute__((ext_vector_type(4))) float f32x4;    // 16x16 MFMA C/D frag
typedef __attribute__((ext_vector_type(16))) float f32x16;  // 32x32 MFMA C/D frag
typedef __attribute__((ext_vector_type(4))) unsigned u32x4;

#define B_  2
#define L_  2048
#define D_  1024
#define H_  16
#define HD_ 64
#define BH_ 32
#define L2E 1.4426950408889634f

#define DEV static __device__ __forceinline__

DEV short f2bf(float f) {
    bf16 h = __float2bfloat16(f);
    return __builtin_bit_cast(short, h);
}

DEV unsigned pk2(float lo, float hi) {   // bf16(lo) | bf16(hi)<<16
    unsigned a = (unsigned short)__builtin_bit_cast(unsigned short, __float2bfloat16(lo));
    unsigned b = (unsigned short)__builtin_bit_cast(unsigned short, __float2bfloat16(hi));
    return a | (b << 16);
}

DEV f32x4 mfma16(bf16x8 a, bf16x8 b, f32x4 c) {
    return __builtin_amdgcn_mfma_f32_16x16x32_bf16(a, b, c, 0, 0, 0);
}
DEV f32x16 mfma32(bf16x8 a, bf16x8 b, f32x16 c) {
    return __builtin_amdgcn_mfma_f32_32x32x16_bf16(a, b, c, 0, 0, 0);
}

// async global->LDS, 16B per lane; lds ptr must be wave-uniform (HW adds lane*16)
DEV void async_ld16(const void* g, void* lds_uniform) {
    __builtin_amdgcn_global_load_lds((const __attribute__((address_space(1))) void*)g,
                                     (__attribute__((address_space(3))) void*)lds_uniform,
                                     16, 0, 0);
}

// XOR-swizzled element offset inside a [rows][64] bf16 tile (128B rows).
DEV int swz(int row, int col) {
    int blk = (row << 3) + (col >> 3);
    blk ^= (row & 7);
    return (blk << 3) + (col & 7);
}

// ---------------------------------------------------------------- cast x -> bf16
__global__ __launch_bounds__(256) void k_cast_x(const float* __restrict__ x,
                                                bf16* __restrict__ xb, int n8) {
    int i = blockIdx.x * 256 + threadIdx.x;
    if (i >= n8) return;
    const float4* src = (const float4*)x + (size_t)i * 2;
    float4 a = src[0], b = src[1];
    bf16x8 v;
    v[0]=f2bf(a.x); v[1]=f2bf(a.y); v[2]=f2bf(a.z); v[3]=f2bf(a.w);
    v[4]=f2bf(b.x); v[5]=f2bf(b.y); v[6]=f2bf(b.z); v[7]=f2bf(b.w);
    *(bf16x8*)(xb + (size_t)i * 8) = v;
}

// ------------------------------------------- cast + transpose weights -> WT[n][k] bf16
__global__ __launch_bounds__(256) void k_cast_wT(const float* __restrict__ W0, const float* __restrict__ W1,
                                                 const float* __restrict__ W2, const float* __restrict__ W3,
                                                 bf16* __restrict__ WT) {
    const float* W = (blockIdx.z == 0) ? W0 : (blockIdx.z == 1) ? W1 : (blockIdx.z == 2) ? W2 : W3;
    __shared__ float tile[64][65];
    const int r0 = blockIdx.y * 64, c0 = blockIdx.x * 64;
    const int tx = threadIdx.x & 63, ty = threadIdx.x >> 6;
    #pragma unroll
    for (int i = 0; i < 16; ++i) {
        int r = ty + i * 4;
        tile[r][tx] = W[(size_t)(r0 + r) * D_ + c0 + tx];
    }
    __syncthreads();
    bf16* out = WT + (size_t)blockIdx.z * D_ * D_;
    #pragma unroll
    for (int i = 0; i < 16; ++i) {
        int n = ty + i * 4;
        out[(size_t)(c0 + n) * D_ + r0 + tx] = __float2bfloat16(tile[tx][n]);
    }
}

// ---------------------------------------------------------------- GEMM 128x128, BK=64
template <int MODE>
__global__ __launch_bounds__(256) void k_gemm(const bf16* __restrict__ A, const bf16* __restrict__ BT,
                                              void* __restrict__ C) {
    __shared__ __align__(16) bf16 As[128 * 64];
    __shared__ __align__(16) bf16 Bs[128 * 64];
    const int t = threadIdx.x;
    const int w = t >> 6, lane = t & 63;
    const int lr = lane & 15, lg = lane >> 4;
    const int wr = (w >> 1) * 64, wc = (w & 1) * 64;
    const size_t am0 = (size_t)blockIdx.y * 128;
    const size_t bn0 = (size_t)blockIdx.x * 128;

    f32x4 acc[4][4] = {};

    for (int kt = 0; kt < 1024 / 64; ++kt) {
        const int k0 = kt * 64;
        if (kt) __syncthreads();
        #pragma unroll
        for (int c = 0; c < 4; ++c) {
            int phys = c * 256 + t;
            int lb = phys ^ ((phys >> 3) & 7);
            int row = lb >> 3, cb = lb & 7;
            int ldsoff = (c * 256 + w * 64) * 8;
            async_ld16(A  + (am0 + row) * 1024 + k0 + cb * 8, (void*)(As + ldsoff));
            async_ld16(BT + (bn0 + row) * 1024 + k0 + cb * 8, (void*)(Bs + ldsoff));
        }
        __syncthreads();
        bf16x8 af[4][2], bfv[4][2];
        #pragma unroll
        for (int mi = 0; mi < 4; ++mi)
            #pragma unroll
            for (int ks = 0; ks < 2; ++ks)
                af[mi][ks] = *(const bf16x8*)(As + swz(wr + mi * 16 + lr, ks * 32 + lg * 8));
        #pragma unroll
        for (int ni = 0; ni < 4; ++ni)
            #pragma unroll
            for (int ks = 0; ks < 2; ++ks)
                bfv[ni][ks] = *(const bf16x8*)(Bs + swz(wc + ni * 16 + lr, ks * 32 + lg * 8));
        #pragma unroll
        for (int mi = 0; mi < 4; ++mi)
            #pragma unroll
            for (int ni = 0; ni < 4; ++ni) {
                acc[mi][ni] = mfma16(af[mi][0], bfv[ni][0], acc[mi][ni]);
                acc[mi][ni] = mfma16(af[mi][1], bfv[ni][1], acc[mi][ni]);
            }
    }

    #pragma unroll
    for (int mi = 0; mi < 4; ++mi)
        #pragma unroll
        for (int ni = 0; ni < 4; ++ni)
            #pragma unroll
            for (int j = 0; j < 4; ++j) {
                size_t gm = am0 + wr + mi * 16 + lg * 4 + j;
                size_t gn = bn0 + wc + ni * 16 + lr;
                float v = acc[mi][ni][j];
                if (MODE == 0) {
                    int which = (int)(gn >> 10);
                    int h = (int)((gn >> 6) & 15);
                    int d = (int)(gn & 63);
                    int bb = (int)(gm >> 11);
                    int l = (int)(gm & 2047);
                    // fold 0.125 * log2(e) into Q so attention works in exp2 domain
                    if (which == 0) v *= 0.18033688011112042f;
                    bf16* dst = (bf16*)C + (size_t)which * ((size_t)BH_ * L_ * HD_);
                    dst[((size_t)(bb * H_ + h) * L_ + l) * HD_ + d] = __float2bfloat16(v);
                } else {
                    ((float*)C)[gm * 1024 + gn] = v;
                }
            }
}

// ---------------------------------------------------------------- V transpose per head
__global__ __launch_bounds__(256) void k_transpose_v(const bf16* __restrict__ Vb, bf16* __restrict__ VTb) {
    __shared__ __align__(16) short tile[64][80];
    const int bh = blockIdx.y;
    const int l0 = blockIdx.x * 64;
    const int t = threadIdx.x;
    const int rr = t >> 2, cc = (t & 3) * 16;
    const short* src = (const short*)(Vb + ((size_t)bh * L_ + l0 + rr) * HD_ + cc);
    *(bf16x8*)&tile[rr][cc]     = *(const bf16x8*)src;
    *(bf16x8*)&tile[rr][cc + 8] = *(const bf16x8*)(src + 8);
    __syncthreads();
    bf16x8 v0, v1;
    #pragma unroll
    for (int i = 0; i < 8; ++i) v0[i] = tile[cc + i][rr];
    #pragma unroll
    for (int i = 0; i < 8; ++i) v1[i] = tile[cc + 8 + i][rr];
    short* dst = (short*)(VTb + ((size_t)bh * HD_ + rr) * L_ + l0 + cc);
    *(bf16x8*)dst       = v0;
    *(bf16x8*)(dst + 8) = v1;
}

// ---------------------------------------------------------------- fused attention
// grid 1024 (XCD-swizzled: 2 heads x both batches per XCD), 256 thr = 4 waves = (qs,kvh).
// Wave: 32 q-rows (q0=qt*64+qs*32), batch bb (per block), kv half kvh (1024 kv, 32 tiles).
// K[kvh]: [32 kv][64 d] 128B rows XOR-swizzled, shared by qs-waves.
// V: [64 d][kvh0 32kv | kvh1 32kv] 128B rows, shared by all 4 waves (conflict-free like K).
// PE: per-lane float4 x4 -> regs, depth-2; b-blocks re-read same lines (L2, same XCD).
// 8 VMEM/wave/tile -> uniform vmcnt(8); 2 barriers/tile; in-block kvh merge epilogue.
__global__ __launch_bounds__(256, 4) void k_attn(const bf16* __restrict__ Qb, const bf16* __restrict__ Kb,
                                                 const bf16* __restrict__ VTb, const float* __restrict__ PE,
                                                 bf16* __restrict__ Ob) {
    __shared__ __align__(16) char shm[32768];   // [2 buf][ K: 2x4KB | V: 8KB ]

    const int bid = blockIdx.x;
    const int sw  = (bid & 7) * 128 + (bid >> 3);   // bijective (1024 = 8*128)
    const int qt  = sw & 31, bb = (sw >> 5) & 1, h = sw >> 6;
    const int t   = threadIdx.x;
    const int w   = t >> 6, l = t & 63;
    const int qs  = w & 1, kvh = w >> 1;
    const int q0  = qt * 64 + qs * 32;
    const int lq  = l & 31;         // this lane's q-row
    const int lh  = l >> 5;         // half selector within wave

    // pi(lq): involution swapping 4-blocks 1<->2 and 5<->6 (A-row m holds K[pi(m)])
    const int pb = (lq >> 2) & 3;
    const int prow = lq + (pb == 1 ? 4 : (pb == 2 ? -4 : 0));

    // Q B-fragments, hoisted (Q pre-scaled by 0.125*log2e at projection)
    bf16x8 Qf[4];
    #pragma unroll
    for (int dm = 0; dm < 4; ++dm)
        Qf[dm] = *(const bf16x8*)(Qb + ((size_t)(bb * H_ + h) * L_ + q0 + lq) * HD_ + dm * 16 + lh * 8);

    const bf16*  kb    = Kb  + (size_t)(bb * H_ + h) * L_ * HD_ + (size_t)kvh * 1024 * HD_;
    const bf16*  vbase = VTb + (size_t)(bb * H_ + h) * HD_ * L_;
    const float* perow = PE  + ((size_t)h * L_ + q0 + lq) * L_ + kvh * 1024;

    // ---- staging source offsets (pre-swizzled; rule #21) ----
    const int k_srcoff = (l >> 3) * HD_ + (((l & 7) ^ (l >> 3)) * 8);
    const int vlb = (l & 7) ^ (l >> 3);                         // logical 16B block 0..7
    const size_t v_lane = (size_t)(l >> 3) * L_ + (vlb >> 2) * 1024 + (vlb & 3) * 8;
    // ---- PE per-lane float4 offsets within a 32-kv tile (pi mapping, R6-verified) ----
    int peoff[4];
    #pragma unroll
    for (int g = 0; g < 4; ++g)
        peoff[g] = (g >> 1) * 16 + (g & 1) * 4 + lh * 8;

    // ---- LDS read offsets (swizzled) ----
    int kro[4];
    #pragma unroll
    for (int dm = 0; dm < 4; ++dm)
        kro[dm] = prow * 64 + (((dm * 2 + lh) ^ (prow & 7)) * 8);
    int vro[2][2];
    #pragma unroll
    for (int d0 = 0; d0 < 2; ++d0)
        #pragma unroll
        for (int m = 0; m < 2; ++m)
            vro[d0][m] = (d0 * 32 + lq) * 64 + (((kvh * 4 + m * 2 + lh) ^ (lq & 7)) * 8);

#define SH_K(BUF) (shm + (BUF) * 16384 + kvh * 4096)
#define SH_V(BUF) (shm + (BUF) * 16384 + 8192)

    f32x16 o[2] = {};
    float mrun = -3e38f, lpart = 0.f;
    float4 pe0[4], pe1[4];

#define STAGE(BUF, TILE) {                                                              \
    const int kv0_ = (TILE) * 32;                                                       \
    _Pragma("unroll") for (int i = 0; i < 2; ++i) {                                     \
        const int c = 2 * qs + i;                                                       \
        async_ld16(kb + (size_t)(kv0_ + c * 8) * HD_ + k_srcoff, (void*)(SH_K(BUF) + c * 1024)); \
    }                                                                                   \
    _Pragma("unroll") for (int i = 0; i < 2; ++i) {                                     \
        const int cv = 2 * w + i;                                                       \
        async_ld16(vbase + v_lane + (size_t)(cv * 8) * L_ + kv0_, (void*)(SH_V(BUF) + cv * 1024)); \
    }                                                                                   \
}

#define PELOAD(DST, TILE) {                                                             \
    _Pragma("unroll") for (int g = 0; g < 4; ++g)                                       \
        DST[g] = *(const float4*)(perow + (size_t)(TILE) * 32 + peoff[g]);              \
}

#define COMPUTE(BUF, PEA) {                                                             \
    const bf16* KL = (const bf16*)SH_K(BUF);                                            \
    const bf16* VL = (const bf16*)SH_V(BUF);                                            \
    bf16x8 kf0_ = *(const bf16x8*)(KL + kro[0]);                                        \
    bf16x8 kf1_ = *(const bf16x8*)(KL + kro[1]);                                        \
    bf16x8 kf2_ = *(const bf16x8*)(KL + kro[2]);                                        \
    bf16x8 kf3_ = *(const bf16x8*)(KL + kro[3]);                                        \
    f32x16 s = {};                                                                      \
    s = mfma32(kf0_, Qf[0], s);                                                         \
    s = mfma32(kf1_, Qf[1], s);                                                         \
    s = mfma32(kf2_, Qf[2], s);                                                         \
    s = mfma32(kf3_, Qf[3], s);                                                         \
    float v_[16];                                                                       \
    _Pragma("unroll") for (int r = 0; r < 16; ++r)                                      \
        v_[r] = fmaf(PEA[r >> 2][r & 3], L2E, s[r]);                                    \
    float t0_ = fmaxf(fmaxf(v_[0], v_[1]), fmaxf(v_[2], v_[3]));                        \
    float t1_ = fmaxf(fmaxf(v_[4], v_[5]), fmaxf(v_[6], v_[7]));                        \
    float t2_ = fmaxf(fmaxf(v_[8], v_[9]), fmaxf(v_[10], v_[11]));                      \
    float t3_ = fmaxf(fmaxf(v_[12], v_[13]), fmaxf(v_[14], v_[15]));                    \
    float vmh_ = fmaxf(fmaxf(t0_, t1_), fmaxf(t2_, t3_));                               \
    float vm_ = fmaxf(vmh_, __shfl_xor(vmh_, 32, 64));                                  \
    float mold_ = mrun;                                                                 \
    float mnew_ = mold_;                                                                \
    if (!__all(vm_ <= mold_ + 10.f)) {                                                  \
        mnew_ = fmaxf(mold_, vm_);                                                      \
        float scl_ = __builtin_amdgcn_exp2f(mold_ - mnew_);                             \
        mrun = mnew_;                                                                   \
        lpart *= scl_;                                                                  \
        _Pragma("unroll") for (int r = 0; r < 16; ++r) { o[0][r] *= scl_; o[1][r] *= scl_; } \
    }                                                                                   \
    float p_[16], ssum_ = 0.f;                                                          \
    _Pragma("unroll") for (int r = 0; r < 16; ++r) {                                    \
        p_[r] = __builtin_amdgcn_exp2f(v_[r] - mnew_);                                  \
        ssum_ += p_[r];                                                                 \
    }                                                                                   \
    lpart += ssum_;                                                                     \
    unsigned a_[8];                                                                     \
    _Pragma("unroll") for (int j = 0; j < 8; ++j)                                       \
        a_[j] = pk2(p_[2 * j], p_[2 * j + 1]);                                          \
    u32x4 w0v_ = { a_[0], a_[1], a_[2], a_[3] };                                        \
    u32x4 w1v_ = { a_[4], a_[5], a_[6], a_[7] };                                        \
    bf16x8 pf0_ = __builtin_bit_cast(bf16x8, w0v_);                                     \
    bf16x8 pf1_ = __builtin_bit_cast(bf16x8, w1v_);                                     \
    o[0] = mfma32(*(const bf16x8*)(VL + vro[0][0]), pf0_, o[0]);                        \
    o[0] = mfma32(*(const bf16x8*)(VL + vro[0][1]), pf1_, o[0]);                        \
    o[1] = mfma32(*(const bf16x8*)(VL + vro[1][0]), pf0_, o[1]);                        \
    o[1] = mfma32(*(const bf16x8*)(VL + vro[1][1]), pf1_, o[1]);                        \
}

    // ---- prologue: stage tiles 0 (buf0), 1 (buf1) + PE ----
    STAGE(0, 0)
    PELOAD(pe0, 0)
    STAGE(1, 1)
    PELOAD(pe1, 1)

    for (int tp = 0; tp < 16; ++tp) {
        const int e = 2 * tp;
        const int fA = (e + 2 < 32) ? e + 2 : 31;
        const int fB = (e + 3 < 32) ? e + 3 : 31;
        asm volatile("s_waitcnt vmcnt(8)" ::: "memory");   // tile e ready (own 8 oldest)
        __builtin_amdgcn_s_barrier();                      // everyone's tile e ready
        COMPUTE(0, pe0)
        __builtin_amdgcn_s_barrier();                      // all waves done reading buf0
        STAGE(0, fA)
        PELOAD(pe0, fA)
        asm volatile("s_waitcnt vmcnt(8)" ::: "memory");   // tile e+1 ready
        __builtin_amdgcn_s_barrier();
        COMPUTE(1, pe1)
        __builtin_amdgcn_s_barrier();
        STAGE(1, fB)
        PELOAD(pe1, fB)
    }
#undef COMPUTE
#undef PELOAD
#undef STAGE
#undef SH_K
#undef SH_V

    // drain dangling DMA before LDS reuse
    asm volatile("s_waitcnt vmcnt(0)" ::: "memory");

    // combine l across lane-halves (same q-row; m already uniform across halves)
    float lsum = lpart + __shfl_xor(lpart, 32, 64);

    // ---- in-block kvh merge: kvh=1 dumps, kvh=0 merges + stores ----
    __syncthreads();
    float* mg = (float*)shm;          // 2 regions (qs) x 64 lanes x 34 floats = 17408 floats? (2*2176)
    if (kvh == 1) {
        float* d = mg + qs * 2176 + l * 34;
        #pragma unroll
        for (int r = 0; r < 16; ++r) { d[r] = o[0][r]; d[16 + r] = o[1][r]; }
        d[32] = mrun; d[33] = lsum;
    }
    __syncthreads();
    if (kvh == 0) {
        const float* s = mg + qs * 2176 + l * 34;
        float m1 = s[32], l1 = s[33];
        float ms = fmaxf(mrun, m1);
        float c0 = __builtin_amdgcn_exp2f(mrun - ms);
        float c1 = __builtin_amdgcn_exp2f(m1 - ms);
        float inv = __builtin_amdgcn_rcpf(lsum * c0 + l1 * c1);
        #pragma unroll
        for (int d0 = 0; d0 < 2; ++d0)
            #pragma unroll
            for (int r = 0; r < 16; r += 2) {
                float e0 = (o[d0][r]     * c0 + s[d0 * 16 + r]     * c1) * inv;
                float e1 = (o[d0][r + 1] * c0 + s[d0 * 16 + r + 1] * c1) * inv;
                int d = d0 * 32 + ((r & 3) + 8 * (r >> 2)) + lh * 4;
                *(unsigned*)(Ob + ((size_t)bb * L_ + q0 + lq) * D_ + h * HD_ + d) = pk2(e0, e1);
            }
    }
}

// ---------------------------------------------------------------- launch
extern "C" void kernel_launch(void* const* d_in, const int* in_sizes, int n_in,
                              void* d_out, int out_size, void* d_ws, size_t ws_size,
                              hipStream_t stream) {
    const float* x  = (const float*)d_in[0];
    const float* pe = (const float*)d_in[1];
    const float* Wq = (const float*)d_in[2];
    const float* Wk = (const float*)d_in[3];
    const float* Wv = (const float*)d_in[4];
    const float* Wo = (const float*)d_in[5];
    float* out = (float*)d_out;

    const size_t MD = (size_t)4096 * 1024;
    const size_t HS = (size_t)BH_ * L_ * HD_;

    bf16* Xb  = (bf16*)d_ws;        // x in bf16            [4096][1024]
    bf16* WT  = Xb + MD;            // WqT|WkT|WvT|WoT      [4096][1024]
    bf16* Qb  = WT + MD;            // [bh][L][64]  (pre-scaled by 0.125*log2e)
    bf16* Kb  = Qb + HS;
    bf16* Vb  = Kb + HS;
    bf16* VTb = Vb + HS;            // [bh][64][L]
    bf16* Ob  = VTb + HS;           // attention out        [4096][1024]

    k_cast_x<<<2048, 256, 0, stream>>>(x, Xb, 4096 * 1024 / 8);
    k_cast_wT<<<dim3(16, 16, 4), 256, 0, stream>>>(Wq, Wk, Wv, Wo, WT);
    k_gemm<0><<<dim3(24, 32), 256, 0, stream>>>(Xb, WT, (void*)Qb);          // QKV, N=3072
    k_transpose_v<<<dim3(32, 32), 256, 0, stream>>>(Vb, VTb);
    k_attn<<<1024, 256, 0, stream>>>(Qb, Kb, VTb, pe, Ob);
    k_gemm<1><<<dim3(8, 32), 256, 0, stream>>>(Ob, WT + (size_t)3072 * 1024, (void*)out); // out-proj
}

// Round 10
// 166.743 us; speedup vs baseline: 1.9501x; 1.9501x over previous
//
#include <hip/hip_runtime.h>
#include <hip/hip_bf16.h>
#include <stdint.h>

typedef __hip_bfloat16 bf16;
typedef __attribute__((ext_vector_type(8))) short bf16x8;   // 8 bf16 = 4 VGPRs (MFMA A/B frag)
typedef __attribute__((ext_vector_type(4))) float f32x4;    // 16x16 MFMA C/D frag
typedef __attribute__((ext_vector_type(16))) float f32x16;  // 32x32 MFMA C/D frag
typedef __attribute__((ext_vector_type(4))) unsigned u32x4;

#define B_  2
#define L_  2048
#define D_  1024
#define H_  16
#define HD_ 64
#define BH_ 32
#define L2E 1.4426950408889634f

#define DEV static __device__ __forceinline__

DEV short f2bf(float f) {
    bf16 h = __float2bfloat16(f);
    return __builtin_bit_cast(short, h);
}

DEV unsigned pk2(float lo, float hi) {   // bf16(lo) | bf16(hi)<<16
    unsigned a = (unsigned short)__builtin_bit_cast(unsigned short, __float2bfloat16(lo));
    unsigned b = (unsigned short)__builtin_bit_cast(unsigned short, __float2bfloat16(hi));
    return a | (b << 16);
}

DEV f32x4 mfma16(bf16x8 a, bf16x8 b, f32x4 c) {
    return __builtin_amdgcn_mfma_f32_16x16x32_bf16(a, b, c, 0, 0, 0);
}
DEV f32x16 mfma32(bf16x8 a, bf16x8 b, f32x16 c) {
    return __builtin_amdgcn_mfma_f32_32x32x16_bf16(a, b, c, 0, 0, 0);
}

// async global->LDS, 16B per lane; lds ptr must be wave-uniform (HW adds lane*16)
DEV void async_ld16(const void* g, void* lds_uniform) {
    __builtin_amdgcn_global_load_lds((const __attribute__((address_space(1))) void*)g,
                                     (__attribute__((address_space(3))) void*)lds_uniform,
                                     16, 0, 0);
}

// XOR-swizzled element offset inside a [rows][64] bf16 tile (128B rows).
DEV int swz(int row, int col) {
    int blk = (row << 3) + (col >> 3);
    blk ^= (row & 7);
    return (blk << 3) + (col & 7);
}

// ---------------------------------------------------------------- cast x -> bf16
__global__ __launch_bounds__(256) void k_cast_x(const float* __restrict__ x,
                                                bf16* __restrict__ xb, int n8) {
    int i = blockIdx.x * 256 + threadIdx.x;
    if (i >= n8) return;
    const float4* src = (const float4*)x + (size_t)i * 2;
    float4 a = src[0], b = src[1];
    bf16x8 v;
    v[0]=f2bf(a.x); v[1]=f2bf(a.y); v[2]=f2bf(a.z); v[3]=f2bf(a.w);
    v[4]=f2bf(b.x); v[5]=f2bf(b.y); v[6]=f2bf(b.z); v[7]=f2bf(b.w);
    *(bf16x8*)(xb + (size_t)i * 8) = v;
}

// ------------------------------------------- cast + transpose weights -> WT[n][k] bf16
__global__ __launch_bounds__(256) void k_cast_wT(const float* __restrict__ W0, const float* __restrict__ W1,
                                                 const float* __restrict__ W2, const float* __restrict__ W3,
                                                 bf16* __restrict__ WT) {
    const float* W = (blockIdx.z == 0) ? W0 : (blockIdx.z == 1) ? W1 : (blockIdx.z == 2) ? W2 : W3;
    __shared__ float tile[64][65];
    const int r0 = blockIdx.y * 64, c0 = blockIdx.x * 64;
    const int tx = threadIdx.x & 63, ty = threadIdx.x >> 6;
    #pragma unroll
    for (int i = 0; i < 16; ++i) {
        int r = ty + i * 4;
        tile[r][tx] = W[(size_t)(r0 + r) * D_ + c0 + tx];
    }
    __syncthreads();
    bf16* out = WT + (size_t)blockIdx.z * D_ * D_;
    #pragma unroll
    for (int i = 0; i < 16; ++i) {
        int n = ty + i * 4;
        out[(size_t)(c0 + n) * D_ + r0 + tx] = __float2bfloat16(tile[tx][n]);
    }
}

// ---------------------------------------------------------------- GEMM 128x128, BK=64
template <int MODE>
__global__ __launch_bounds__(256) void k_gemm(const bf16* __restrict__ A, const bf16* __restrict__ BT,
                                              void* __restrict__ C) {
    __shared__ __align__(16) bf16 As[128 * 64];
    __shared__ __align__(16) bf16 Bs[128 * 64];
    const int t = threadIdx.x;
    const int w = t >> 6, lane = t & 63;
    const int lr = lane & 15, lg = lane >> 4;
    const int wr = (w >> 1) * 64, wc = (w & 1) * 64;
    const size_t am0 = (size_t)blockIdx.y * 128;
    const size_t bn0 = (size_t)blockIdx.x * 128;

    f32x4 acc[4][4] = {};

    for (int kt = 0; kt < 1024 / 64; ++kt) {
        const int k0 = kt * 64;
        if (kt) __syncthreads();
        #pragma unroll
        for (int c = 0; c < 4; ++c) {
            int phys = c * 256 + t;
            int lb = phys ^ ((phys >> 3) & 7);
            int row = lb >> 3, cb = lb & 7;
            int ldsoff = (c * 256 + w * 64) * 8;
            async_ld16(A  + (am0 + row) * 1024 + k0 + cb * 8, (void*)(As + ldsoff));
            async_ld16(BT + (bn0 + row) * 1024 + k0 + cb * 8, (void*)(Bs + ldsoff));
        }
        __syncthreads();
        bf16x8 af[4][2], bfv[4][2];
        #pragma unroll
        for (int mi = 0; mi < 4; ++mi)
            #pragma unroll
            for (int ks = 0; ks < 2; ++ks)
                af[mi][ks] = *(const bf16x8*)(As + swz(wr + mi * 16 + lr, ks * 32 + lg * 8));
        #pragma unroll
        for (int ni = 0; ni < 4; ++ni)
            #pragma unroll
            for (int ks = 0; ks < 2; ++ks)
                bfv[ni][ks] = *(const bf16x8*)(Bs + swz(wc + ni * 16 + lr, ks * 32 + lg * 8));
        #pragma unroll
        for (int mi = 0; mi < 4; ++mi)
            #pragma unroll
            for (int ni = 0; ni < 4; ++ni) {
                acc[mi][ni] = mfma16(af[mi][0], bfv[ni][0], acc[mi][ni]);
                acc[mi][ni] = mfma16(af[mi][1], bfv[ni][1], acc[mi][ni]);
            }
    }

    #pragma unroll
    for (int mi = 0; mi < 4; ++mi)
        #pragma unroll
        for (int ni = 0; ni < 4; ++ni)
            #pragma unroll
            for (int j = 0; j < 4; ++j) {
                size_t gm = am0 + wr + mi * 16 + lg * 4 + j;
                size_t gn = bn0 + wc + ni * 16 + lr;
                float v = acc[mi][ni][j];
                if (MODE == 0) {
                    int which = (int)(gn >> 10);
                    int h = (int)((gn >> 6) & 15);
                    int d = (int)(gn & 63);
                    int bb = (int)(gm >> 11);
                    int l = (int)(gm & 2047);
                    // fold 0.125 * log2(e) into Q so attention works in exp2 domain
                    if (which == 0) v *= 0.18033688011112042f;
                    bf16* dst = (bf16*)C + (size_t)which * ((size_t)BH_ * L_ * HD_);
                    dst[((size_t)(bb * H_ + h) * L_ + l) * HD_ + d] = __float2bfloat16(v);
                } else {
                    ((float*)C)[gm * 1024 + gn] = v;
                }
            }
}

// ---------------------------------------------------------------- V transpose per head
__global__ __launch_bounds__(256) void k_transpose_v(const bf16* __restrict__ Vb, bf16* __restrict__ VTb) {
    __shared__ __align__(16) short tile[64][80];
    const int bh = blockIdx.y;
    const int l0 = blockIdx.x * 64;
    const int t = threadIdx.x;
    const int rr = t >> 2, cc = (t & 3) * 16;
    const short* src = (const short*)(Vb + ((size_t)bh * L_ + l0 + rr) * HD_ + cc);
    *(bf16x8*)&tile[rr][cc]     = *(const bf16x8*)src;
    *(bf16x8*)&tile[rr][cc + 8] = *(const bf16x8*)(src + 8);
    __syncthreads();
    bf16x8 v0, v1;
    #pragma unroll
    for (int i = 0; i < 8; ++i) v0[i] = tile[cc + i][rr];
    #pragma unroll
    for (int i = 0; i < 8; ++i) v1[i] = tile[cc + 8 + i][rr];
    short* dst = (short*)(VTb + ((size_t)bh * HD_ + rr) * L_ + l0 + cc);
    *(bf16x8*)dst       = v0;
    *(bf16x8*)(dst + 8) = v1;
}

// ---------------------------------------------------------------- fused attention
// grid 512 (XCD-swizzled: 2 heads/XCD), 256 thr = 4 waves = (qs,b). Wave: 32 q-rows,
// full 2048 kv (64 tiles of 32), one batch. TRIPLE-buffered LDS (24KB/buf):
//   K [b][32kv x 128B] swizzled (2 DMA/wave), V [64d x 128B (b0|b1)] (2 DMA/wave),
//   PE [qs][32q x 32kv f32] coalesced (2 DMA/wave) -- NO per-lane scattered PE loads.
// 6 DMA/wave/step -> counted vmcnt(12) = 2 full compute-steps of flight, never drained.
// Compute: R4..R8-verified pi-permuted 32x32 in-register softmax.
__global__ __launch_bounds__(256, 2) void k_attn(const bf16* __restrict__ Qb, const bf16* __restrict__ Kb,
                                                 const bf16* __restrict__ VTb, const float* __restrict__ PE,
                                                 bf16* __restrict__ Ob) {
    __shared__ __align__(16) char shm[73728];   // 3 bufs x [K 8KB | V 8KB | PE 8KB]

    const int bid = blockIdx.x;
    const int sw  = (bid & 7) * 64 + (bid >> 3);   // XCD swizzle (bijective, 512 = 8*64)
    const int qt  = sw & 31, h = sw >> 5;
    const int t   = threadIdx.x;
    const int w   = t >> 6, l = t & 63;
    const int qs  = w & 1, b = w >> 1;
    const int q0  = qt * 64 + qs * 32;
    const int lq  = l & 31;         // this lane's q-row
    const int lh  = l >> 5;         // half selector within wave

    // pi(lq): involution swapping 4-blocks 1<->2 and 5<->6 (A-row m holds K[pi(m)])
    const int pb = (lq >> 2) & 3;
    const int prow = lq + (pb == 1 ? 4 : (pb == 2 ? -4 : 0));

    // Q B-fragments, hoisted (Q pre-scaled by 0.125*log2e at projection)
    bf16x8 Qf[4];
    #pragma unroll
    for (int dm = 0; dm < 4; ++dm)
        Qf[dm] = *(const bf16x8*)(Qb + ((size_t)(b * H_ + h) * L_ + q0 + lq) * HD_ + dm * 16 + lh * 8);

    const bf16*  kb    = Kb  + (size_t)(b * H_ + h) * L_ * HD_;
    const bf16*  vbase = VTb + (size_t)h * HD_ * L_;            // batch via lane offset
    const float* peq   = PE  + ((size_t)h * L_ + q0) * L_;      // this wave's 32 q-rows (via qs in q0)

    // ---- staging source offsets (pre-swizzled; rule #21) ----
    const int k_srcoff  = (l >> 3) * HD_ + (((l & 7) ^ (l >> 3)) * 8);          // bf16 elems
    const int vlb = (l & 7) ^ (l >> 3);                                         // logical 16B block
    const size_t v_lane = (size_t)(vlb >> 2) * ((size_t)H_ * HD_ * L_)          // batch select
                        + (size_t)(l >> 3) * L_ + (vlb & 3) * 8;                // d-row + kv chunk
    const int pe_srcoff = (l >> 3) * L_ + (((l & 7) ^ (l >> 3)) * 4);           // floats

    // ---- LDS read offsets (swizzled) ----
    int kro[4];
    #pragma unroll
    for (int dm = 0; dm < 4; ++dm)
        kro[dm] = prow * 64 + (((dm * 2 + lh) ^ (prow & 7)) * 8);
    int vro[2][2];
    #pragma unroll
    for (int d0 = 0; d0 < 2; ++d0)
        #pragma unroll
        for (int m = 0; m < 2; ++m)
            vro[d0][m] = (d0 * 32 + lq) * 64 + (((b * 4 + m * 2 + lh) ^ (lq & 7)) * 8);
    int peo[4];   // float idx: row lq (128B), logical 16B slot s=(g>>1)*4+(g&1)+lh*2, swizzled
    #pragma unroll
    for (int g = 0; g < 4; ++g)
        peo[g] = lq * 32 + ((((g >> 1) * 4 + (g & 1) + lh * 2) ^ (lq & 7)) * 4);

#define SH_K(BUF)  (shm + (BUF) * 24576 + b * 4096)
#define SH_V(BUF)  (shm + (BUF) * 24576 + 8192)
#define SH_PE(BUF) (shm + (BUF) * 24576 + 16384 + qs * 4096)

    f32x16 o[2] = {};
    float mrun = -3e38f, lpart = 0.f;

#define STAGE(BUF, TILE) {                                                              \
    const int kv0_ = (TILE) * 32;                                                       \
    _Pragma("unroll") for (int i = 0; i < 2; ++i) {                                     \
        const int c = 2 * qs + i;                                                       \
        async_ld16(kb + (size_t)(kv0_ + c * 8) * HD_ + k_srcoff, (void*)(SH_K(BUF) + c * 1024)); \
    }                                                                                   \
    _Pragma("unroll") for (int i = 0; i < 2; ++i) {                                     \
        const int cv = 2 * w + i;                                                       \
        async_ld16(vbase + v_lane + (size_t)(cv * 8) * L_ + kv0_, (void*)(SH_V(BUF) + cv * 1024)); \
    }                                                                                   \
    _Pragma("unroll") for (int i = 0; i < 2; ++i) {                                     \
        const int c = 2 * b + i;                                                        \
        async_ld16(peq + (size_t)(c * 8) * L_ + kv0_ + pe_srcoff, (void*)(SH_PE(BUF) + c * 1024)); \
    }                                                                                   \
}

#define COMPUTE(BUF) {                                                                  \
    const bf16*  KL = (const bf16*)SH_K(BUF);                                           \
    const bf16*  VL = (const bf16*)SH_V(BUF);                                           \
    const float* PL = (const float*)SH_PE(BUF);                                         \
    bf16x8 kf0_ = *(const bf16x8*)(KL + kro[0]);                                        \
    bf16x8 kf1_ = *(const bf16x8*)(KL + kro[1]);                                        \
    bf16x8 kf2_ = *(const bf16x8*)(KL + kro[2]);                                        \
    bf16x8 kf3_ = *(const bf16x8*)(KL + kro[3]);                                        \
    f32x16 s = {};                                                                      \
    s = mfma32(kf0_, Qf[0], s);                                                         \
    s = mfma32(kf1_, Qf[1], s);                                                         \
    s = mfma32(kf2_, Qf[2], s);                                                         \
    s = mfma32(kf3_, Qf[3], s);                                                         \
    float4 pef_[4];                                                                     \
    _Pragma("unroll") for (int g = 0; g < 4; ++g)                                       \
        pef_[g] = *(const float4*)(PL + peo[g]);                                        \
    float v_[16];                                                                       \
    _Pragma("unroll") for (int r = 0; r < 16; ++r)                                      \
        v_[r] = fmaf(pef_[r >> 2][r & 3], L2E, s[r]);                                   \
    float t0_ = fmaxf(fmaxf(v_[0], v_[1]), fmaxf(v_[2], v_[3]));                        \
    float t1_ = fmaxf(fmaxf(v_[4], v_[5]), fmaxf(v_[6], v_[7]));                        \
    float t2_ = fmaxf(fmaxf(v_[8], v_[9]), fmaxf(v_[10], v_[11]));                      \
    float t3_ = fmaxf(fmaxf(v_[12], v_[13]), fmaxf(v_[14], v_[15]));                    \
    float vmh_ = fmaxf(fmaxf(t0_, t1_), fmaxf(t2_, t3_));                               \
    float vm_ = fmaxf(vmh_, __shfl_xor(vmh_, 32, 64));                                  \
    float mold_ = mrun;                                                                 \
    float mnew_ = mold_;                                                                \
    if (!__all(vm_ <= mold_ + 10.f)) {                                                  \
        mnew_ = fmaxf(mold_, vm_);                                                      \
        float scl_ = __builtin_amdgcn_exp2f(mold_ - mnew_);                             \
        mrun = mnew_;                                                                   \
        lpart *= scl_;                                                                  \
        _Pragma("unroll") for (int r = 0; r < 16; ++r) { o[0][r] *= scl_; o[1][r] *= scl_; } \
    }                                                                                   \
    float p_[16], ssum_ = 0.f;                                                          \
    _Pragma("unroll") for (int r = 0; r < 16; ++r) {                                    \
        p_[r] = __builtin_amdgcn_exp2f(v_[r] - mnew_);                                  \
        ssum_ += p_[r];                                                                 \
    }                                                                                   \
    lpart += ssum_;                                                                     \
    unsigned a_[8];                                                                     \
    _Pragma("unroll") for (int j = 0; j < 8; ++j)                                       \
        a_[j] = pk2(p_[2 * j], p_[2 * j + 1]);                                          \
    u32x4 w0v_ = { a_[0], a_[1], a_[2], a_[3] };                                        \
    u32x4 w1v_ = { a_[4], a_[5], a_[6], a_[7] };                                        \
    bf16x8 pf0_ = __builtin_bit_cast(bf16x8, w0v_);                                     \
    bf16x8 pf1_ = __builtin_bit_cast(bf16x8, w1v_);                                     \
    o[0] = mfma32(*(const bf16x8*)(VL + vro[0][0]), pf0_, o[0]);                        \
    o[0] = mfma32(*(const bf16x8*)(VL + vro[0][1]), pf1_, o[0]);                        \
    o[1] = mfma32(*(const bf16x8*)(VL + vro[1][0]), pf0_, o[1]);                        \
    o[1] = mfma32(*(const bf16x8*)(VL + vro[1][1]), pf1_, o[1]);                        \
}

#define STEP(BUF, T, PFT) {                                                             \
    asm volatile("s_waitcnt vmcnt(12)" ::: "memory");   /* tile T landed (own 6) */     \
    __builtin_amdgcn_s_barrier();                       /* everyone's tile T landed */  \
    COMPUTE(BUF)                                                                        \
    __builtin_amdgcn_s_barrier();                       /* all done reading BUF */      \
    STAGE(BUF, PFT)                                                                     \
}

    // ---- prologue: stage tiles 0,1,2 into bufs 0,1,2 (18 outstanding/wave) ----
    STAGE(0, 0)
    STAGE(1, 1)
    STAGE(2, 2)

    // 63 = 21 x 3 steps; tile 63 handled in the tail (buf 63%3 = 0)
    for (int tp = 0; tp < 21; ++tp) {
        const int e = 3 * tp;
        const int f0 = (e + 3 < 64) ? e + 3 : 63;
        const int f1 = (e + 4 < 64) ? e + 4 : 63;
        const int f2 = (e + 5 < 64) ? e + 5 : 63;
        STEP(0, e,     f0)
        STEP(1, e + 1, f1)
        STEP(2, e + 2, f2)
    }
    // tail: compute tile 63 from buf0 (staged at t=60)
    asm volatile("s_waitcnt vmcnt(12)" ::: "memory");
    __builtin_amdgcn_s_barrier();
    COMPUTE(0)
#undef STEP
#undef COMPUTE
#undef STAGE
#undef SH_K
#undef SH_V
#undef SH_PE

    // drain dangling DMA before block retirement
    asm volatile("s_waitcnt vmcnt(0)" ::: "memory");

    // ---- epilogue: combine l across lane-halves, normalize, store ----
    float lsum = lpart + __shfl_xor(lpart, 32, 64);
    float inv = __builtin_amdgcn_rcpf(lsum);
    #pragma unroll
    for (int d0 = 0; d0 < 2; ++d0)
        #pragma unroll
        for (int r = 0; r < 16; r += 2) {
            float e0 = o[d0][r] * inv;
            float e1 = o[d0][r + 1] * inv;
            int d = d0 * 32 + ((r & 3) + 8 * (r >> 2)) + lh * 4;
            *(unsigned*)(Ob + ((size_t)b * L_ + q0 + lq) * D_ + h * HD_ + d) = pk2(e0, e1);
        }
}

// ---------------------------------------------------------------- launch
extern "C" void kernel_launch(void* const* d_in, const int* in_sizes, int n_in,
                              void* d_out, int out_size, void* d_ws, size_t ws_size,
                              hipStream_t stream) {
    const float* x  = (const float*)d_in[0];
    const float* pe = (const float*)d_in[1];
    const float* Wq = (const float*)d_in[2];
    const float* Wk = (const float*)d_in[3];
    const float* Wv = (const float*)d_in[4];
    const float* Wo = (const float*)d_in[5];
    float* out = (float*)d_out;

    const size_t MD = (size_t)4096 * 1024;
    const size_t HS = (size_t)BH_ * L_ * HD_;

    bf16* Xb  = (bf16*)d_ws;        // x in bf16            [4096][1024]
    bf16* WT  = Xb + MD;            // WqT|WkT|WvT|WoT      [4096][1024]
    bf16* Qb  = WT + MD;            // [bh][L][64]  (pre-scaled by 0.125*log2e)
    bf16* Kb  = Qb + HS;
    bf16* Vb  = Kb + HS;
    bf16* VTb = Vb + HS;            // [bh][64][L]
    bf16* Ob  = VTb + HS;           // attention out        [4096][1024]

    k_cast_x<<<2048, 256, 0, stream>>>(x, Xb, 4096 * 1024 / 8);
    k_cast_wT<<<dim3(16, 16, 4), 256, 0, stream>>>(Wq, Wk, Wv, Wo, WT);
    k_gemm<0><<<dim3(24, 32), 256, 0, stream>>>(Xb, WT, (void*)Qb);          // QKV, N=3072
    k_transpose_v<<<dim3(32, 32), 256, 0, stream>>>(Vb, VTb);
    k_attn<<<512, 256, 0, stream>>>(Qb, Kb, VTb, pe, Ob);
    k_gemm<1><<<dim3(8, 32), 256, 0, stream>>>(Ob, WT + (size_t)3072 * 1024, (void*)out); // out-proj
}

// Round 11
// 160.137 us; speedup vs baseline: 2.0305x; 1.0413x over previous
//
#include <hip/hip_runtime.h>
#include <hip/hip_bf16.h>
#include <stdint.h>

typedef __hip_bfloat16 bf16;
typedef __attribute__((ext_vector_type(8))) short bf16x8;   // 8 bf16 = 4 VGPRs (MFMA A/B frag)
typedef __attribute__((ext_vector_type(4))) float f32x4;    // 16x16 MFMA C/D frag
typedef __attribute__((ext_vector_type(16))) float f32x16;  // 32x32 MFMA C/D frag
typedef __attribute__((ext_vector_type(4))) unsigned u32x4;

#define B_  2
#define L_  2048
#define D_  1024
#define H_  16
#define HD_ 64
#define BH_ 32
#define L2E 1.4426950408889634f
#define HSZ ((size_t)BH_ * L_ * HD_)

#define DEV static __device__ __forceinline__

DEV short f2bf(float f) {
    bf16 h = __float2bfloat16(f);
    return __builtin_bit_cast(short, h);
}

DEV unsigned pk2(float lo, float hi) {   // bf16(lo) | bf16(hi)<<16
    unsigned a = (unsigned short)__builtin_bit_cast(unsigned short, __float2bfloat16(lo));
    unsigned b = (unsigned short)__builtin_bit_cast(unsigned short, __float2bfloat16(hi));
    return a | (b << 16);
}

DEV f32x4 mfma16(bf16x8 a, bf16x8 b, f32x4 c) {
    return __builtin_amdgcn_mfma_f32_16x16x32_bf16(a, b, c, 0, 0, 0);
}
DEV f32x16 mfma32(bf16x8 a, bf16x8 b, f32x16 c) {
    return __builtin_amdgcn_mfma_f32_32x32x16_bf16(a, b, c, 0, 0, 0);
}

// async global->LDS, 16B per lane; lds ptr must be wave-uniform (HW adds lane*16)
DEV void async_ld16(const void* g, void* lds_uniform) {
    __builtin_amdgcn_global_load_lds((const __attribute__((address_space(1))) void*)g,
                                     (__attribute__((address_space(3))) void*)lds_uniform,
                                     16, 0, 0);
}

// XOR-swizzled element offset inside a [rows][64] bf16 tile (128B rows).
DEV int swz(int row, int col) {
    int blk = (row << 3) + (col >> 3);
    blk ^= (row & 7);
    return (blk << 3) + (col & 7);
}

// ---------------------------------------------------------------- cast x -> bf16
__global__ __launch_bounds__(256) void k_cast_x(const float* __restrict__ x,
                                                bf16* __restrict__ xb, int n8) {
    int i = blockIdx.x * 256 + threadIdx.x;
    if (i >= n8) return;
    const float4* src = (const float4*)x + (size_t)i * 2;
    float4 a = src[0], b = src[1];
    bf16x8 v;
    v[0]=f2bf(a.x); v[1]=f2bf(a.y); v[2]=f2bf(a.z); v[3]=f2bf(a.w);
    v[4]=f2bf(b.x); v[5]=f2bf(b.y); v[6]=f2bf(b.z); v[7]=f2bf(b.w);
    *(bf16x8*)(xb + (size_t)i * 8) = v;
}

// ------------------------------------------- cast + transpose weights -> WT[n][k] bf16
__global__ __launch_bounds__(256) void k_cast_wT(const float* __restrict__ W0, const float* __restrict__ W1,
                                                 const float* __restrict__ W2, const float* __restrict__ W3,
                                                 bf16* __restrict__ WT) {
    const float* W = (blockIdx.z == 0) ? W0 : (blockIdx.z == 1) ? W1 : (blockIdx.z == 2) ? W2 : W3;
    __shared__ float tile[64][65];
    const int r0 = blockIdx.y * 64, c0 = blockIdx.x * 64;
    const int tx = threadIdx.x & 63, ty = threadIdx.x >> 6;
    #pragma unroll
    for (int i = 0; i < 16; ++i) {
        int r = ty + i * 4;
        tile[r][tx] = W[(size_t)(r0 + r) * D_ + c0 + tx];
    }
    __syncthreads();
    bf16* out = WT + (size_t)blockIdx.z * D_ * D_;
    #pragma unroll
    for (int i = 0; i < 16; ++i) {
        int n = ty + i * 4;
        out[(size_t)(c0 + n) * D_ + r0 + tx] = __float2bfloat16(tile[tx][n]);
    }
}

// ---------------------------------------------------------------- GEMM TMx128, BK=64
// MODE 0 (TM=128): QKV; Q/K scattered bf16, V stored TRANSPOSED into the VTb slot.
// MODE 1 (TM=64): f32 out, 64-row tiles -> 512 blocks = 2/CU (inter-block overlap).
template <int MODE, int TM>
__global__ __launch_bounds__(256) void k_gemm(const bf16* __restrict__ A, const bf16* __restrict__ BT,
                                              void* __restrict__ C) {
    constexpr int MI = TM / 32;            // 16-row frags per wave (rows/wave = TM/2)
    __shared__ __align__(16) bf16 As[TM * 64];
    __shared__ __align__(16) bf16 Bs[128 * 64];
    const int t = threadIdx.x;
    const int w = t >> 6, lane = t & 63;
    const int lr = lane & 15, lg = lane >> 4;
    const int wr = (w >> 1) * (TM / 2), wc = (w & 1) * 64;
    const size_t am0 = (size_t)blockIdx.y * TM;
    const size_t bn0 = (size_t)blockIdx.x * 128;

    f32x4 acc[MI][4] = {};

    for (int kt = 0; kt < 1024 / 64; ++kt) {
        const int k0 = kt * 64;
        if (kt) __syncthreads();
        #pragma unroll
        for (int c = 0; c < TM / 32; ++c) {            // A tile: TM x 64
            int phys = c * 256 + t;
            int lb = phys ^ ((phys >> 3) & 7);
            int row = lb >> 3, cb = lb & 7;
            int ldsoff = (c * 256 + w * 64) * 8;
            async_ld16(A + (am0 + row) * 1024 + k0 + cb * 8, (void*)(As + ldsoff));
        }
        #pragma unroll
        for (int c = 0; c < 4; ++c) {                  // B tile: 128 x 64
            int phys = c * 256 + t;
            int lb = phys ^ ((phys >> 3) & 7);
            int row = lb >> 3, cb = lb & 7;
            int ldsoff = (c * 256 + w * 64) * 8;
            async_ld16(BT + (bn0 + row) * 1024 + k0 + cb * 8, (void*)(Bs + ldsoff));
        }
        __syncthreads();
        bf16x8 af[MI][2], bfv[4][2];
        #pragma unroll
        for (int mi = 0; mi < MI; ++mi)
            #pragma unroll
            for (int ks = 0; ks < 2; ++ks)
                af[mi][ks] = *(const bf16x8*)(As + swz(wr + mi * 16 + lr, ks * 32 + lg * 8));
        #pragma unroll
        for (int ni = 0; ni < 4; ++ni)
            #pragma unroll
            for (int ks = 0; ks < 2; ++ks)
                bfv[ni][ks] = *(const bf16x8*)(Bs + swz(wc + ni * 16 + lr, ks * 32 + lg * 8));
        #pragma unroll
        for (int mi = 0; mi < MI; ++mi)
            #pragma unroll
            for (int ni = 0; ni < 4; ++ni) {
                acc[mi][ni] = mfma16(af[mi][0], bfv[ni][0], acc[mi][ni]);
                acc[mi][ni] = mfma16(af[mi][1], bfv[ni][1], acc[mi][ni]);
            }
    }

    #pragma unroll
    for (int mi = 0; mi < MI; ++mi)
        #pragma unroll
        for (int ni = 0; ni < 4; ++ni) {
            const size_t gm0 = am0 + wr + mi * 16 + lg * 4;   // first of 4 consecutive rows
            const size_t gn  = bn0 + wc + ni * 16 + lr;
            float v0 = acc[mi][ni][0], v1 = acc[mi][ni][1];
            float v2 = acc[mi][ni][2], v3 = acc[mi][ni][3];
            if (MODE == 1) {
                float* dst = (float*)C + gm0 * 1024 + gn;
                dst[0] = v0; dst[1024] = v1; dst[2048] = v2; dst[3072] = v3;
            } else {
                const int which = (int)(gn >> 10);            // wave-uniform (block of 16 cols)
                const int hh = (int)((gn >> 6) & 15);
                const int d  = (int)(gn & 63);
                const int bbb = (int)(gm0 >> 11);
                const int ll  = (int)(gm0 & 2047);
                if (which == 2) {
                    // V: store transposed into the VTb slot (C + 3*HSZ): row d, cols ll..ll+3
                    bf16* vdst = (bf16*)C + 3 * HSZ + ((size_t)(bbb * H_ + hh) * HD_ + d) * L_ + ll;
                    uint2 pv;
                    pv.x = pk2(v0, v1);
                    pv.y = pk2(v2, v3);
                    *(uint2*)vdst = pv;
                } else {
                    // Q (pre-scaled into exp2 domain) / K: row-major [bh][L][64]
                    float s = (which == 0) ? 0.18033688011112042f : 1.0f;
                    bf16* dst = (bf16*)C + (size_t)which * HSZ
                              + ((size_t)(bbb * H_ + hh) * L_ + ll) * HD_ + d;
                    dst[0]   = __float2bfloat16(v0 * s);
                    dst[64]  = __float2bfloat16(v1 * s);
                    dst[128] = __float2bfloat16(v2 * s);
                    dst[192] = __float2bfloat16(v3 * s);
                }
            }
        }
}

// ---------------------------------------------------------------- fused attention
// (unchanged from R10 -- verified) grid 512, 4 waves (qs,b), triple-buffered 24KB bufs,
// 6 DMA/wave/step, counted vmcnt(12), pi-permuted 32x32 in-register softmax.
__global__ __launch_bounds__(256, 2) void k_attn(const bf16* __restrict__ Qb, const bf16* __restrict__ Kb,
                                                 const bf16* __restrict__ VTb, const float* __restrict__ PE,
                                                 bf16* __restrict__ Ob) {
    __shared__ __align__(16) char shm[73728];   // 3 bufs x [K 8KB | V 8KB | PE 8KB]

    const int bid = blockIdx.x;
    const int sw  = (bid & 7) * 64 + (bid >> 3);   // XCD swizzle (bijective, 512 = 8*64)
    const int qt  = sw & 31, h = sw >> 5;
    const int t   = threadIdx.x;
    const int w   = t >> 6, l = t & 63;
    const int qs  = w & 1, b = w >> 1;
    const int q0  = qt * 64 + qs * 32;
    const int lq  = l & 31;
    const int lh  = l >> 5;

    const int pb = (lq >> 2) & 3;
    const int prow = lq + (pb == 1 ? 4 : (pb == 2 ? -4 : 0));

    bf16x8 Qf[4];
    #pragma unroll
    for (int dm = 0; dm < 4; ++dm)
        Qf[dm] = *(const bf16x8*)(Qb + ((size_t)(b * H_ + h) * L_ + q0 + lq) * HD_ + dm * 16 + lh * 8);

    const bf16*  kb    = Kb  + (size_t)(b * H_ + h) * L_ * HD_;
    const bf16*  vbase = VTb + (size_t)h * HD_ * L_;
    const float* peq   = PE  + ((size_t)h * L_ + q0) * L_;

    const int k_srcoff  = (l >> 3) * HD_ + (((l & 7) ^ (l >> 3)) * 8);
    const int vlb = (l & 7) ^ (l >> 3);
    const size_t v_lane = (size_t)(vlb >> 2) * ((size_t)H_ * HD_ * L_)
                        + (size_t)(l >> 3) * L_ + (vlb & 3) * 8;
    const int pe_srcoff = (l >> 3) * L_ + (((l & 7) ^ (l >> 3)) * 4);

    int kro[4];
    #pragma unroll
    for (int dm = 0; dm < 4; ++dm)
        kro[dm] = prow * 64 + (((dm * 2 + lh) ^ (prow & 7)) * 8);
    int vro[2][2];
    #pragma unroll
    for (int d0 = 0; d0 < 2; ++d0)
        #pragma unroll
        for (int m = 0; m < 2; ++m)
            vro[d0][m] = (d0 * 32 + lq) * 64 + (((b * 4 + m * 2 + lh) ^ (lq & 7)) * 8);
    int peo[4];
    #pragma unroll
    for (int g = 0; g < 4; ++g)
        peo[g] = lq * 32 + ((((g >> 1) * 4 + (g & 1) + lh * 2) ^ (lq & 7)) * 4);

#define SH_K(BUF)  (shm + (BUF) * 24576 + b * 4096)
#define SH_V(BUF)  (shm + (BUF) * 24576 + 8192)
#define SH_PE(BUF) (shm + (BUF) * 24576 + 16384 + qs * 4096)

    f32x16 o[2] = {};
    float mrun = -3e38f, lpart = 0.f;

#define STAGE(BUF, TILE) {                                                              \
    const int kv0_ = (TILE) * 32;                                                       \
    _Pragma("unroll") for (int i = 0; i < 2; ++i) {                                     \
        const int c = 2 * qs + i;                                                       \
        async_ld16(kb + (size_t)(kv0_ + c * 8) * HD_ + k_srcoff, (void*)(SH_K(BUF) + c * 1024)); \
    }                                                                                   \
    _Pragma("unroll") for (int i = 0; i < 2; ++i) {                                     \
        const int cv = 2 * w + i;                                                       \
        async_ld16(vbase + v_lane + (size_t)(cv * 8) * L_ + kv0_, (void*)(SH_V(BUF) + cv * 1024)); \
    }                                                                                   \
    _Pragma("unroll") for (int i = 0; i < 2; ++i) {                                     \
        const int c = 2 * b + i;                                                        \
        async_ld16(peq + (size_t)(c * 8) * L_ + kv0_ + pe_srcoff, (void*)(SH_PE(BUF) + c * 1024)); \
    }                                                                                   \
}

#define COMPUTE(BUF) {                                                                  \
    const bf16*  KL = (const bf16*)SH_K(BUF);                                           \
    const bf16*  VL = (const bf16*)SH_V(BUF);                                           \
    const float* PL = (const float*)SH_PE(BUF);                                         \
    bf16x8 kf0_ = *(const bf16x8*)(KL + kro[0]);                                        \
    bf16x8 kf1_ = *(const bf16x8*)(KL + kro[1]);                                        \
    bf16x8 kf2_ = *(const bf16x8*)(KL + kro[2]);                                        \
    bf16x8 kf3_ = *(const bf16x8*)(KL + kro[3]);                                        \
    f32x16 s = {};                                                                      \
    s = mfma32(kf0_, Qf[0], s);                                                         \
    s = mfma32(kf1_, Qf[1], s);                                                         \
    s = mfma32(kf2_, Qf[2], s);                                                         \
    s = mfma32(kf3_, Qf[3], s);                                                         \
    float4 pef_[4];                                                                     \
    _Pragma("unroll") for (int g = 0; g < 4; ++g)                                       \
        pef_[g] = *(const float4*)(PL + peo[g]);                                        \
    float v_[16];                                                                       \
    _Pragma("unroll") for (int r = 0; r < 16; ++r)                                      \
        v_[r] = fmaf(pef_[r >> 2][r & 3], L2E, s[r]);                                   \
    float t0_ = fmaxf(fmaxf(v_[0], v_[1]), fmaxf(v_[2], v_[3]));                        \
    float t1_ = fmaxf(fmaxf(v_[4], v_[5]), fmaxf(v_[6], v_[7]));                        \
    float t2_ = fmaxf(fmaxf(v_[8], v_[9]), fmaxf(v_[10], v_[11]));                      \
    float t3_ = fmaxf(fmaxf(v_[12], v_[13]), fmaxf(v_[14], v_[15]));                    \
    float vmh_ = fmaxf(fmaxf(t0_, t1_), fmaxf(t2_, t3_));                               \
    float vm_ = fmaxf(vmh_, __shfl_xor(vmh_, 32, 64));                                  \
    float mold_ = mrun;                                                                 \
    float mnew_ = mold_;                                                                \
    if (!__all(vm_ <= mold_ + 10.f)) {                                                  \
        mnew_ = fmaxf(mold_, vm_);                                                      \
        float scl_ = __builtin_amdgcn_exp2f(mold_ - mnew_);                             \
        mrun = mnew_;                                                                   \
        lpart *= scl_;                                                                  \
        _Pragma("unroll") for (int r = 0; r < 16; ++r) { o[0][r] *= scl_; o[1][r] *= scl_; } \
    }                                                                                   \
    float p_[16], ssum_ = 0.f;                                                          \
    _Pragma("unroll") for (int r = 0; r < 16; ++r) {                                    \
        p_[r] = __builtin_amdgcn_exp2f(v_[r] - mnew_);                                  \
        ssum_ += p_[r];                                                                 \
    }                                                                                   \
    lpart += ssum_;                                                                     \
    unsigned a_[8];                                                                     \
    _Pragma("unroll") for (int j = 0; j < 8; ++j)                                       \
        a_[j] = pk2(p_[2 * j], p_[2 * j + 1]);                                          \
    u32x4 w0v_ = { a_[0], a_[1], a_[2], a_[3] };                                        \
    u32x4 w1v_ = { a_[4], a_[5], a_[6], a_[7] };                                        \
    bf16x8 pf0_ = __builtin_bit_cast(bf16x8, w0v_);                                     \
    bf16x8 pf1_ = __builtin_bit_cast(bf16x8, w1v_);                                     \
    o[0] = mfma32(*(const bf16x8*)(VL + vro[0][0]), pf0_, o[0]);                        \
    o[0] = mfma32(*(const bf16x8*)(VL + vro[0][1]), pf1_, o[0]);                        \
    o[1] = mfma32(*(const bf16x8*)(VL + vro[1][0]), pf0_, o[1]);                        \
    o[1] = mfma32(*(const bf16x8*)(VL + vro[1][1]), pf1_, o[1]);                        \
}

#define STEP(BUF, T, PFT) {                                                             \
    asm volatile("s_waitcnt vmcnt(12)" ::: "memory");                                   \
    __builtin_amdgcn_s_barrier();                                                       \
    COMPUTE(BUF)                                                                        \
    __builtin_amdgcn_s_barrier();                                                       \
    STAGE(BUF, PFT)                                                                     \
}

    STAGE(0, 0)
    STAGE(1, 1)
    STAGE(2, 2)

    for (int tp = 0; tp < 21; ++tp) {
        const int e = 3 * tp;
        const int f0 = (e + 3 < 64) ? e + 3 : 63;
        const int f1 = (e + 4 < 64) ? e + 4 : 63;
        const int f2 = (e + 5 < 64) ? e + 5 : 63;
        STEP(0, e,     f0)
        STEP(1, e + 1, f1)
        STEP(2, e + 2, f2)
    }
    asm volatile("s_waitcnt vmcnt(12)" ::: "memory");
    __builtin_amdgcn_s_barrier();
    COMPUTE(0)
#undef STEP
#undef COMPUTE
#undef STAGE
#undef SH_K
#undef SH_V
#undef SH_PE

    asm volatile("s_waitcnt vmcnt(0)" ::: "memory");

    float lsum = lpart + __shfl_xor(lpart, 32, 64);
    float inv = __builtin_amdgcn_rcpf(lsum);
    #pragma unroll
    for (int d0 = 0; d0 < 2; ++d0)
        #pragma unroll
        for (int r = 0; r < 16; r += 2) {
            float e0 = o[d0][r] * inv;
            float e1 = o[d0][r + 1] * inv;
            int d = d0 * 32 + ((r & 3) + 8 * (r >> 2)) + lh * 4;
            *(unsigned*)(Ob + ((size_t)b * L_ + q0 + lq) * D_ + h * HD_ + d) = pk2(e0, e1);
        }
}

// ---------------------------------------------------------------- launch
extern "C" void kernel_launch(void* const* d_in, const int* in_sizes, int n_in,
                              void* d_out, int out_size, void* d_ws, size_t ws_size,
                              hipStream_t stream) {
    const float* x  = (const float*)d_in[0];
    const float* pe = (const float*)d_in[1];
    const float* Wq = (const float*)d_in[2];
    const float* Wk = (const float*)d_in[3];
    const float* Wv = (const float*)d_in[4];
    const float* Wo = (const float*)d_in[5];
    float* out = (float*)d_out;

    const size_t MD = (size_t)4096 * 1024;

    bf16* Xb  = (bf16*)d_ws;        // x in bf16            [4096][1024]
    bf16* WT  = Xb + MD;            // WqT|WkT|WvT|WoT      [4096][1024]
    bf16* Qb  = WT + MD;            // [bh][L][64]  (pre-scaled by 0.125*log2e)
    bf16* Kb  = Qb + HSZ;
    bf16* Vb  = Kb + HSZ;           // (unused slot; V goes straight to VTb)
    bf16* VTb = Vb + HSZ;           // [bh][64][L]  (written by k_gemm<0> transposed)
    bf16* Ob  = VTb + HSZ;          // attention out        [4096][1024]

    k_cast_x<<<2048, 256, 0, stream>>>(x, Xb, 4096 * 1024 / 8);
    k_cast_wT<<<dim3(16, 16, 4), 256, 0, stream>>>(Wq, Wk, Wv, Wo, WT);
    k_gemm<0, 128><<<dim3(24, 32), 256, 0, stream>>>(Xb, WT, (void*)Qb);     // QKV (V -> VTb)
    k_attn<<<512, 256, 0, stream>>>(Qb, Kb, VTb, pe, Ob);
    k_gemm<1, 64><<<dim3(8, 64), 256, 0, stream>>>(Ob, WT + (size_t)3072 * 1024, (void*)out);
}